// Round 9
// baseline (188.266 us; speedup 1.0000x reference)
//
#include <hip/hip_runtime.h>

typedef __attribute__((ext_vector_type(8))) short bf16x8;
typedef __attribute__((ext_vector_type(4))) float f32x4;
typedef __attribute__((ext_vector_type(16))) float f32x16;
typedef __attribute__((ext_vector_type(2))) unsigned u32x2;

// ---------- bf16 helpers (RNE) ----------
__device__ __forceinline__ unsigned short f2b(float f) {
  union { float f; unsigned u; } x; x.f = f;
  unsigned r = x.u + 0x7fffu + ((x.u >> 16) & 1u);
  return (unsigned short)(r >> 16);
}

// pack two floats -> one dword of 2x bf16 via HW cvt_pk (lane-local asm)
__device__ __forceinline__ int cvt_pk_bf16(float lo, float hi) {
  int r;
  asm("v_cvt_pk_bf16_f32 %0, %1, %2" : "=v"(r) : "v"(lo), "v"(hi));
  return r;
}

__device__ __forceinline__ float exp2_fast(float x) {
#if __has_builtin(__builtin_amdgcn_exp2f)
  return __builtin_amdgcn_exp2f(x);
#else
  return __expf(x * 0.69314718055994531f);
#endif
}

// ---------- async global->LDS 16B ----------
__device__ __forceinline__ void gl_lds16(const unsigned short* g, unsigned short* l) {
  __builtin_amdgcn_global_load_lds(
      (const __attribute__((address_space(1))) unsigned int*)(unsigned long long)g,
      (__attribute__((address_space(3))) unsigned int*)(unsigned)(unsigned long long)l,
      16, 0, 0);
}

#define MFMA(a, b, c) __builtin_amdgcn_mfma_f32_16x16x32_bf16((a), (b), (c), 0, 0, 0)
#define MFMA32(a, b, c) __builtin_amdgcn_mfma_f32_32x32x16_bf16((a), (b), (c), 0, 0, 0)

// ==================== convert x: fp32 -> bf16 ====================
__global__ __launch_bounds__(256) void convert_x(const float* __restrict__ x,
                                                 unsigned short* __restrict__ xb) {
  int i = (blockIdx.x * 256 + threadIdx.x) * 4;
  float4 v = *(const float4*)(x + i);
  ushort4 o;
  o.x = f2b(v.x); o.y = f2b(v.y); o.z = f2b(v.z); o.w = f2b(v.w);
  *(ushort4*)(xb + i) = o;
}

// ==================== transpose weights: W[K][N] fp32 -> WT[N][K] bf16 ====================
__global__ __launch_bounds__(256) void transpose_w(const float* __restrict__ wq, const float* __restrict__ wk,
                                                   const float* __restrict__ wv, const float* __restrict__ wo,
                                                   unsigned short* __restrict__ tq, unsigned short* __restrict__ tk,
                                                   unsigned short* __restrict__ tv, unsigned short* __restrict__ to_) {
  int z = blockIdx.z;
  const float* W = (z == 0) ? wq : (z == 1) ? wk : (z == 2) ? wv : wo;
  unsigned short* T = (z == 0) ? tq : (z == 1) ? tk : (z == 2) ? tv : to_;
  // fold 1/sqrt(64) AND log2(e) into Wq so softmax uses exp2 directly
  float scale = (z == 0) ? 0.125f * 1.4426950408889634f : 1.0f;
  __shared__ float tile[64][65];
  int tr = blockIdx.y * 64, tc = blockIdx.x * 64;
  int t = threadIdx.x;
  int col = t & 63, r0 = (t >> 6) * 16;
#pragma unroll
  for (int r = 0; r < 16; r++)
    tile[r0 + r][col] = W[(long)(tr + r0 + r) * 1024 + tc + col];
  __syncthreads();
  int k = t & 63, n0 = (t >> 6) * 16;
#pragma unroll
  for (int n = 0; n < 16; n++)
    T[(long)(tc + n0 + n) * 1024 + tr + k] = f2b(tile[k][n0 + n] * scale);
}

// ==================== 128x128 bf16 GEMM tile core (dbuf, 1 barrier/K-step) ====================
__device__ __forceinline__ void gemm_stage128(const unsigned short* __restrict__ A,
                                              const unsigned short* __restrict__ BT,
                                              int m0, int n0, int kt,
                                              unsigned short* As, unsigned short* Bs,
                                              int lane, int wid) {
#pragma unroll
  for (int ii = 0; ii < 2; ii++) {
    int chunk = (wid * 2 + ii) * 64 + lane;  // 0..511
    int row = chunk >> 2, rc = chunk & 3;
    gl_lds16(A + (long)(m0 + row) * 1024 + kt * 32 + rc * 8, As + (wid * 2 + ii) * 512);
    gl_lds16(BT + (long)(n0 + row) * 1024 + kt * 32 + rc * 8, Bs + (wid * 2 + ii) * 512);
  }
}

// As/Bs are [2][128*32] double buffers. Loop: barrier -> prefetch kt+1 into buf^1 -> compute buf.
// Same proven sync structure as the attn kernel (barrier drains own vmcnt; prev reads of buf^1
// completed before the barrier).
__device__ __forceinline__ void gemm_tile_128(const unsigned short* __restrict__ A,
                                              const unsigned short* __restrict__ BT,
                                              int m0, int n0, f32x4 acc[4][4],
                                              unsigned short* As, unsigned short* Bs,
                                              int lane, int wid) {
  const int wr = wid >> 1, wc = wid & 1;
  const int c = lane & 15, g = lane >> 4;
  gemm_stage128(A, BT, m0, n0, 0, As, Bs, lane, wid);
  for (int kt = 0; kt < 32; kt++) {
    int buf = kt & 1;
    const unsigned short* Ab = As + buf * 4096;
    const unsigned short* Bb = Bs + buf * 4096;
    __syncthreads();
    if (kt + 1 < 32)
      gemm_stage128(A, BT, m0, n0, kt + 1, As + (buf ^ 1) * 4096, Bs + (buf ^ 1) * 4096, lane, wid);
    bf16x8 af[4], bfr[4];
#pragma unroll
    for (int mi = 0; mi < 4; mi++)
      af[mi] = *(const bf16x8*)(Ab + (wr * 64 + mi * 16 + c) * 32 + g * 8);
#pragma unroll
    for (int ni = 0; ni < 4; ni++)
      bfr[ni] = *(const bf16x8*)(Bb + (wc * 64 + ni * 16 + c) * 32 + g * 8);
#pragma unroll
    for (int mi = 0; mi < 4; mi++)
#pragma unroll
      for (int ni = 0; ni < 4; ni++)
        acc[mi][ni] = MFMA(af[mi], bfr[ni], acc[mi][ni]);
  }
}

// ==================== fused QKV projection ====================
__global__ __launch_bounds__(256) void gemm_qkv(const unsigned short* __restrict__ xb,
                                                const unsigned short* __restrict__ wtq,
                                                const unsigned short* __restrict__ wtk,
                                                const unsigned short* __restrict__ wtv,
                                                unsigned short* __restrict__ Qw,
                                                unsigned short* __restrict__ Kw,
                                                unsigned short* __restrict__ Vtw) {
  __shared__ unsigned short As[2 * 128 * 32], Bs[2 * 128 * 32];
  // XCD-aware bijective remap: XCD k owns M-block-rows [8k,8k+8) x all 24 N-cols ->
  // A-tiles (2MB) stay L2-resident per XCD; weights (6MB) served from L3.
  int lin = blockIdx.y * 64 + blockIdx.x;          // 0..1535
  int work = (lin & 7) * 192 + (lin >> 3);
  int mb = work / 24, nb = work % 24;
  int m0 = mb * 128;
  int nglob = nb * 128;
  int which = nglob >> 10;
  const unsigned short* BT = (which == 0) ? wtq : (which == 1) ? wtk : wtv;
  int n0 = nglob & 1023;
  int lane = threadIdx.x & 63, wid = threadIdx.x >> 6;
  f32x4 acc[4][4] = {};
  gemm_tile_128(xb, BT, m0, n0, acc, As, Bs, lane, wid);

  const int wr = wid >> 1, wc = wid & 1;
  const int c = lane & 15, g = lane >> 4;
  int b = m0 >> 11;
  int ibase = (m0 & 2047);
#pragma unroll
  for (int mi = 0; mi < 4; mi++) {
    int irow0 = ibase + wr * 64 + mi * 16 + g * 4;
#pragma unroll
    for (int ni = 0; ni < 4; ni++) {
      int nl = n0 + wc * 64 + ni * 16 + c;
      int h = nl >> 6, d = nl & 63;
      if (which == 2) {
        ushort4 pk;
        pk.x = f2b(acc[mi][ni][0]); pk.y = f2b(acc[mi][ni][1]);
        pk.z = f2b(acc[mi][ni][2]); pk.w = f2b(acc[mi][ni][3]);
        *(ushort4*)(Vtw + ((long)(b * 16 + h) * 64 + d) * 2048 + irow0) = pk;
      } else {
        unsigned short* dst = (which == 0) ? Qw : Kw;
#pragma unroll
        for (int r = 0; r < 4; r++)
          dst[((long)(b * 16 + h) * 2048 + irow0 + r) * 64 + d] = f2b(acc[mi][ni][r]);
      }
    }
  }
}

// ==================== flash attention: 8 waves x 32q, 32x32 MFMA, swapped QK^T ====================
__global__ __launch_bounds__(512) void attn(const unsigned short* __restrict__ Qw,
                                            const unsigned short* __restrict__ Kw,
                                            const unsigned short* __restrict__ Vtw,
                                            unsigned short* __restrict__ Ow) {
  // XCD-aware remap: all 8 qt-blocks of one bh land on the same XCD (linear id % 8)
  int ib = blockIdx.y * 8 + blockIdx.x;
  int xcd = ib & 7, j = ib >> 3;      // j in 0..63
  int bh = xcd * 8 + (j >> 3);
  int qt = j & 7;
  int t = threadIdx.x;
  int lane = t & 63, wid = t >> 6;    // wid 0..7
  int c5 = lane & 31, h = lane >> 5;
  __shared__ unsigned short Ks[2][64 * 64];
  __shared__ unsigned short Vs[2][64 * 64];

  // Q frags (B-operand): col=q=c5 (row idx), k-elements d = dK*16 + h*8 + e
  const unsigned short* Qp = Qw + ((long)bh * 2048 + qt * 256 + wid * 32 + c5) * 64 + h * 8;
  bf16x8 qf[4];
#pragma unroll
  for (int dK = 0; dK < 4; dK++) qf[dK] = *(const bf16x8*)(Qp + dK * 16);

  f32x16 oacc0 = {}, oacc1 = {};
  float ls0 = 0.f, ls1 = 0.f, ls2 = 0.f, ls3 = 0.f;

  const unsigned short* Kbase = Kw + (long)bh * 2048 * 64;
  const unsigned short* Vbase = Vtw + (long)bh * 64 * 2048;

  // K tile: [64 kv][64 d], V tile: [64 d][64 kv]; 16B-chunk XOR swizzle (chunk ^= row&7)
  // via pre-swizzled GLOBAL source + linear LDS dest. 512 threads: 1 K + 1 V chunk each.
#define STAGE(jt_, buf_)                                                              \
  {                                                                                   \
    int row = t >> 3, ch = t & 7;                                                     \
    int sw = ch ^ (row & 7);                                                          \
    gl_lds16(Kbase + (long)((jt_) * 64 + row) * 64 + sw * 8, &Ks[buf_][t * 8]);       \
    gl_lds16(Vbase + (long)row * 2048 + (jt_) * 64 + sw * 8, &Vs[buf_][t * 8]);       \
  }

  STAGE(0, 0);

  union FR { int i[4]; bf16x8 v; };

  for (int jt = 0; jt < 32; jt++) {
    int buf = jt & 1;
    __syncthreads();  // drains own vmcnt -> buf ready; prev reads of buf^1 complete
    if (jt + 1 < 32) STAGE(jt + 1, buf ^ 1);

    // S^T = K . Q^T : A-frag = K rows (kv), B-frag = Q rows (q)
    f32x16 s0 = {}, s1 = {};
#pragma unroll
    for (int dK = 0; dK < 4; dK++) {
      int sw = ((dK * 2 + h) ^ (c5 & 7)) * 8;
      bf16x8 k0 = *(const bf16x8*)(&Ks[buf][c5 * 64 + sw]);
      bf16x8 k1 = *(const bf16x8*)(&Ks[buf][c5 * 64 + sw + 2048]);  // kv row +32
      s0 = MFMA32(k0, qf[dK], s0);
      s1 = MFMA32(k1, qf[dK], s1);
    }

    // p = 2^S, lane-local row-sum partials, HW-pack pairs to bf16 dwords
    int pk[2][4][2];
#pragma unroll
    for (int q2 = 0; q2 < 4; q2++) {
      float a0 = exp2_fast(s0[q2 * 4 + 0]), a1 = exp2_fast(s0[q2 * 4 + 1]);
      float a2 = exp2_fast(s0[q2 * 4 + 2]), a3 = exp2_fast(s0[q2 * 4 + 3]);
      ls0 += a0 + a1; ls1 += a2 + a3;
      pk[0][q2][0] = cvt_pk_bf16(a0, a1);
      pk[0][q2][1] = cvt_pk_bf16(a2, a3);
      float b0 = exp2_fast(s1[q2 * 4 + 0]), b1 = exp2_fast(s1[q2 * 4 + 1]);
      float b2 = exp2_fast(s1[q2 * 4 + 2]), b3 = exp2_fast(s1[q2 * 4 + 3]);
      ls2 += b0 + b1; ls3 += b2 + b3;
      pk[1][q2][0] = cvt_pk_bf16(b0, b1);
      pk[1][q2][1] = cvt_pk_bf16(b2, b3);
    }

    // Redistribute P across the h-bit with permlane32_swap and run PV: O^T += V^T . P.
#pragma unroll
    for (int kblk = 0; kblk < 4; kblk++) {
      int kvb = kblk >> 1, e2c = (kblk & 1) * 2;
      u32x2 p0 = __builtin_amdgcn_permlane32_swap((unsigned)pk[kvb][e2c][0],
                                                  (unsigned)pk[kvb][e2c + 1][0], false, false);
      u32x2 p1 = __builtin_amdgcn_permlane32_swap((unsigned)pk[kvb][e2c][1],
                                                  (unsigned)pk[kvb][e2c + 1][1], false, false);
      FR fr;
      fr.i[0] = (int)p0[0];  // w0
      fr.i[1] = (int)p1[0];  // w1
      fr.i[2] = (int)p0[1];  // w2
      fr.i[3] = (int)p1[1];  // w3
      int sw = ((kblk * 2 + h) ^ (c5 & 7)) * 8;
      bf16x8 v0 = *(const bf16x8*)(&Vs[buf][c5 * 64 + sw]);
      bf16x8 v1 = *(const bf16x8*)(&Vs[buf][c5 * 64 + sw + 2048]);  // d row +32
      oacc0 = MFMA32(v0, fr.v, oacc0);
      oacc1 = MFMA32(v1, fr.v, oacc1);
    }
  }
#undef STAGE

  // epilogue: full row-sum (other 32 kv in h-partner lane), normalize, store
  float lsum = ls0 + ls1 + ls2 + ls3;
  lsum += __shfl_xor(lsum, 32);
  float inv = 1.0f / lsum;
  int b = bh >> 4, hh = bh & 15;
  long row = (long)b * 2048 + qt * 256 + wid * 32 + c5;
  unsigned short* orow = Ow + row * 1024 + hh * 64;
#pragma unroll
  for (int dblk = 0; dblk < 2; dblk++) {
#pragma unroll
    for (int q2 = 0; q2 < 4; q2++) {
      float o0 = (dblk ? oacc1 : oacc0)[q2 * 4 + 0] * inv;
      float o1 = (dblk ? oacc1 : oacc0)[q2 * 4 + 1] * inv;
      float o2 = (dblk ? oacc1 : oacc0)[q2 * 4 + 2] * inv;
      float o3 = (dblk ? oacc1 : oacc0)[q2 * 4 + 3] * inv;
      ushort4 pkv;
      pkv.x = f2b(o0); pkv.y = f2b(o1); pkv.z = f2b(o2); pkv.w = f2b(o3);
      *(ushort4*)(orow + dblk * 32 + q2 * 8 + h * 4) = pkv;
    }
  }
}

// ==================== output projection + bias ====================
__global__ __launch_bounds__(256) void gemm_out(const unsigned short* __restrict__ Ao,
                                                const unsigned short* __restrict__ wto,
                                                const float* __restrict__ bias,
                                                float* __restrict__ out) {
  __shared__ unsigned short As[2 * 128 * 32], Bs[2 * 128 * 32];
  // XCD-aware bijective remap: XCD k owns M-block-rows [8k,8k+8) x all 8 N-cols
  // (A 2MB + wto 2MB = 4MB, fits one XCD L2).
  int lin = blockIdx.y * 64 + blockIdx.x;          // 0..511
  int work = (lin & 7) * 64 + (lin >> 3);
  int mb = work / 8, nb = work % 8;
  int m0 = mb * 128;
  int n0 = nb * 128;
  int lane = threadIdx.x & 63, wid = threadIdx.x >> 6;
  f32x4 acc[4][4] = {};
  gemm_tile_128(Ao, wto, m0, n0, acc, As, Bs, lane, wid);
  const int wr = wid >> 1, wc = wid & 1;
  const int c = lane & 15, g = lane >> 4;
#pragma unroll
  for (int mi = 0; mi < 4; mi++)
#pragma unroll
    for (int ni = 0; ni < 4; ni++) {
      int col = n0 + wc * 64 + ni * 16 + c;
      float bv = bias[col];
#pragma unroll
      for (int r = 0; r < 4; r++) {
        int row = m0 + wr * 64 + mi * 16 + g * 4 + r;
        out[(long)row * 1024 + col] = acc[mi][ni][r] + bv;
      }
    }
}

// ==================== launch ====================
extern "C" void kernel_launch(void* const* d_in, const int* in_sizes, int n_in,
                              void* d_out, int out_size, void* d_ws, size_t ws_size,
                              hipStream_t stream) {
  const float* x  = (const float*)d_in[0];
  const float* Wq = (const float*)d_in[1];
  const float* Wk = (const float*)d_in[2];
  const float* Wv = (const float*)d_in[3];
  const float* Wo = (const float*)d_in[4];
  const float* bo = (const float*)d_in[5];
  float* out = (float*)d_out;

  char* ws = (char*)d_ws;
  unsigned short* xb  = (unsigned short*)(ws);                              // 16 MB: x bf16 [8192][1024]
  unsigned short* wtq = (unsigned short*)(ws + 16777216);                   // 2 MB each, transposed [N][K]
  unsigned short* wtk = (unsigned short*)(ws + 16777216 + 2097152);
  unsigned short* wtv = (unsigned short*)(ws + 16777216 + 2 * 2097152);
  unsigned short* wto = (unsigned short*)(ws + 16777216 + 3 * 2097152);
  unsigned short* Qw  = (unsigned short*)(ws + 25165824);                   // [bh][i][d]
  unsigned short* Kw  = (unsigned short*)(ws + 25165824 + 16777216);        // [bh][j][d]
  unsigned short* Vtw = (unsigned short*)(ws + 25165824 + 2 * 16777216);    // [bh][d][j]
  unsigned short* Aow = xb;  // alias: xb fully consumed by gemm_qkv before attn writes

  convert_x<<<8192, 256, 0, stream>>>(x, xb);
  transpose_w<<<dim3(16, 16, 4), 256, 0, stream>>>(Wq, Wk, Wv, Wo, wtq, wtk, wtv, wto);
  gemm_qkv<<<dim3(64, 24), 256, 0, stream>>>(xb, wtq, wtk, wtv, Qw, Kw, Vtw);
  attn<<<dim3(8, 64), 512, 0, stream>>>(Qw, Kw, Vtw, Aow);
  gemm_out<<<dim3(64, 8), 256, 0, stream>>>(Aow, wto, bo, out);
}

// Round 10
// 180.665 us; speedup vs baseline: 1.0421x; 1.0421x over previous
//
#include <hip/hip_runtime.h>

typedef __attribute__((ext_vector_type(8))) short bf16x8;
typedef __attribute__((ext_vector_type(4))) float f32x4;
typedef __attribute__((ext_vector_type(16))) float f32x16;
typedef __attribute__((ext_vector_type(2))) unsigned u32x2;

// ---------- bf16 helpers (RNE) ----------
__device__ __forceinline__ unsigned short f2b(float f) {
  union { float f; unsigned u; } x; x.f = f;
  unsigned r = x.u + 0x7fffu + ((x.u >> 16) & 1u);
  return (unsigned short)(r >> 16);
}

// pack two floats -> one dword of 2x bf16 via HW cvt_pk (lane-local asm)
__device__ __forceinline__ int cvt_pk_bf16(float lo, float hi) {
  int r;
  asm("v_cvt_pk_bf16_f32 %0, %1, %2" : "=v"(r) : "v"(lo), "v"(hi));
  return r;
}

__device__ __forceinline__ float exp2_fast(float x) {
#if __has_builtin(__builtin_amdgcn_exp2f)
  return __builtin_amdgcn_exp2f(x);
#else
  return __expf(x * 0.69314718055994531f);
#endif
}

// ---------- async global->LDS 16B ----------
__device__ __forceinline__ void gl_lds16(const unsigned short* g, unsigned short* l) {
  __builtin_amdgcn_global_load_lds(
      (const __attribute__((address_space(1))) unsigned int*)(unsigned long long)g,
      (__attribute__((address_space(3))) unsigned int*)(unsigned)(unsigned long long)l,
      16, 0, 0);
}

#define MFMA(a, b, c) __builtin_amdgcn_mfma_f32_16x16x32_bf16((a), (b), (c), 0, 0, 0)
#define MFMA32(a, b, c) __builtin_amdgcn_mfma_f32_32x32x16_bf16((a), (b), (c), 0, 0, 0)

// ==================== convert x: fp32 -> bf16 ====================
__global__ __launch_bounds__(256) void convert_x(const float* __restrict__ x,
                                                 unsigned short* __restrict__ xb) {
  int i = (blockIdx.x * 256 + threadIdx.x) * 4;
  float4 v = *(const float4*)(x + i);
  ushort4 o;
  o.x = f2b(v.x); o.y = f2b(v.y); o.z = f2b(v.z); o.w = f2b(v.w);
  *(ushort4*)(xb + i) = o;
}

// ==================== transpose weights: W[K][N] fp32 -> WT[N][K] bf16 ====================
__global__ __launch_bounds__(256) void transpose_w(const float* __restrict__ wq, const float* __restrict__ wk,
                                                   const float* __restrict__ wv, const float* __restrict__ wo,
                                                   unsigned short* __restrict__ tq, unsigned short* __restrict__ tk,
                                                   unsigned short* __restrict__ tv, unsigned short* __restrict__ to_) {
  int z = blockIdx.z;
  const float* W = (z == 0) ? wq : (z == 1) ? wk : (z == 2) ? wv : wo;
  unsigned short* T = (z == 0) ? tq : (z == 1) ? tk : (z == 2) ? tv : to_;
  // fold 1/sqrt(64) AND log2(e) into Wq so softmax uses exp2 directly
  float scale = (z == 0) ? 0.125f * 1.4426950408889634f : 1.0f;
  __shared__ float tile[64][65];
  int tr = blockIdx.y * 64, tc = blockIdx.x * 64;
  int t = threadIdx.x;
  int col = t & 63, r0 = (t >> 6) * 16;
#pragma unroll
  for (int r = 0; r < 16; r++)
    tile[r0 + r][col] = W[(long)(tr + r0 + r) * 1024 + tc + col];
  __syncthreads();
  int k = t & 63, n0 = (t >> 6) * 16;
#pragma unroll
  for (int n = 0; n < 16; n++)
    T[(long)(tc + n0 + n) * 1024 + tr + k] = f2b(tile[k][n0 + n] * scale);
}

// ==================== 128x128 bf16 GEMM tile core ====================
// LDS tile [128 rows][4 chunks of 16B]; chunk swizzled: position p holds chunk p^((row>>1)&3).
// Pre-swizzled GLOBAL source + linear LDS dest (gl_lds constraint); reads XOR the same way.
// Quarter-wave (16 lanes) then covers all 8 bank-quads 2-way -> conflict-free.
__device__ __forceinline__ void gemm_stage128(const unsigned short* __restrict__ A,
                                              const unsigned short* __restrict__ BT,
                                              int m0, int n0, int kt,
                                              unsigned short* As, unsigned short* Bs,
                                              int lane, int wid) {
#pragma unroll
  for (int ii = 0; ii < 2; ii++) {
    int chunk = (wid * 2 + ii) * 64 + lane;  // 0..511
    int row = chunk >> 2, rc = chunk & 3;
    int rcs = rc ^ ((row >> 1) & 3);  // source chunk for swizzled position rc
    gl_lds16(A + (long)(m0 + row) * 1024 + kt * 32 + rcs * 8, As + (wid * 2 + ii) * 512);
    gl_lds16(BT + (long)(n0 + row) * 1024 + kt * 32 + rcs * 8, Bs + (wid * 2 + ii) * 512);
  }
}

// 3-buffer pipeline, depth-2 prefetch, counted vmcnt + raw barrier (T3/T4 minimum):
// iter kt: wait own 4 oldest loads (tile kt) -> barrier publishes LDS -> issue tile kt+2
// into buf[(kt+2)%3] (readers of that buffer finished before this barrier) -> compute.
__device__ __forceinline__ void gemm_tile_128(const unsigned short* __restrict__ A,
                                              const unsigned short* __restrict__ BT,
                                              int m0, int n0, f32x4 acc[4][4],
                                              unsigned short* As, unsigned short* Bs,
                                              int lane, int wid) {
  const int wr = wid >> 1, wc = wid & 1;
  const int c = lane & 15, g = lane >> 4;
  gemm_stage128(A, BT, m0, n0, 0, As, Bs, lane, wid);
  gemm_stage128(A, BT, m0, n0, 1, As + 4096, Bs + 4096, lane, wid);
  for (int kt = 0; kt < 32; kt++) {
    int buf = kt % 3;
    const unsigned short* Ab = As + buf * 4096;
    const unsigned short* Bb = Bs + buf * 4096;
    if (kt < 31)
      asm volatile("s_waitcnt vmcnt(4)" ::: "memory");  // tile kt done; kt+1 stays in flight
    else
      asm volatile("s_waitcnt vmcnt(0)" ::: "memory");
    __builtin_amdgcn_s_barrier();
    __builtin_amdgcn_sched_barrier(0);  // no ds_read hoisting above the barrier
    if (kt + 2 < 32) {
      int nb = (kt + 2) % 3;
      gemm_stage128(A, BT, m0, n0, kt + 2, As + nb * 4096, Bs + nb * 4096, lane, wid);
    }
    bf16x8 af[4], bfr[4];
#pragma unroll
    for (int mi = 0; mi < 4; mi++) {
      int row = wr * 64 + mi * 16 + c;
      af[mi] = *(const bf16x8*)(Ab + row * 32 + (g ^ ((row >> 1) & 3)) * 8);
    }
#pragma unroll
    for (int ni = 0; ni < 4; ni++) {
      int row = wc * 64 + ni * 16 + c;
      bfr[ni] = *(const bf16x8*)(Bb + row * 32 + (g ^ ((row >> 1) & 3)) * 8);
    }
#pragma unroll
    for (int mi = 0; mi < 4; mi++)
#pragma unroll
      for (int ni = 0; ni < 4; ni++)
        acc[mi][ni] = MFMA(af[mi], bfr[ni], acc[mi][ni]);
  }
}

// ==================== fused QKV projection ====================
__global__ __launch_bounds__(256) void gemm_qkv(const unsigned short* __restrict__ xb,
                                                const unsigned short* __restrict__ wtq,
                                                const unsigned short* __restrict__ wtk,
                                                const unsigned short* __restrict__ wtv,
                                                unsigned short* __restrict__ Qw,
                                                unsigned short* __restrict__ Kw,
                                                unsigned short* __restrict__ Vtw) {
  __shared__ unsigned short As[3 * 128 * 32], Bs[3 * 128 * 32];
  int m0 = blockIdx.x * 128;
  int nglob = blockIdx.y * 128;
  int which = nglob >> 10;
  const unsigned short* BT = (which == 0) ? wtq : (which == 1) ? wtk : wtv;
  int n0 = nglob & 1023;
  int lane = threadIdx.x & 63, wid = threadIdx.x >> 6;
  f32x4 acc[4][4] = {};
  gemm_tile_128(xb, BT, m0, n0, acc, As, Bs, lane, wid);

  const int wr = wid >> 1, wc = wid & 1;
  const int c = lane & 15, g = lane >> 4;
  int b = m0 >> 11;
  int ibase = (m0 & 2047);
#pragma unroll
  for (int mi = 0; mi < 4; mi++) {
    int irow0 = ibase + wr * 64 + mi * 16 + g * 4;
#pragma unroll
    for (int ni = 0; ni < 4; ni++) {
      int nl = n0 + wc * 64 + ni * 16 + c;
      int h = nl >> 6, d = nl & 63;
      if (which == 2) {
        ushort4 pk;
        pk.x = f2b(acc[mi][ni][0]); pk.y = f2b(acc[mi][ni][1]);
        pk.z = f2b(acc[mi][ni][2]); pk.w = f2b(acc[mi][ni][3]);
        *(ushort4*)(Vtw + ((long)(b * 16 + h) * 64 + d) * 2048 + irow0) = pk;
      } else {
        unsigned short* dst = (which == 0) ? Qw : Kw;
#pragma unroll
        for (int r = 0; r < 4; r++)
          dst[((long)(b * 16 + h) * 2048 + irow0 + r) * 64 + d] = f2b(acc[mi][ni][r]);
      }
    }
  }
}

// ==================== flash attention: 8 waves x 32q, 32x32 MFMA, swapped QK^T ====================
__global__ __launch_bounds__(512) void attn(const unsigned short* __restrict__ Qw,
                                            const unsigned short* __restrict__ Kw,
                                            const unsigned short* __restrict__ Vtw,
                                            unsigned short* __restrict__ Ow) {
  // XCD-aware remap: all 8 qt-blocks of one bh land on the same XCD (linear id % 8)
  int ib = blockIdx.y * 8 + blockIdx.x;
  int xcd = ib & 7, j = ib >> 3;      // j in 0..63
  int bh = xcd * 8 + (j >> 3);
  int qt = j & 7;
  int t = threadIdx.x;
  int lane = t & 63, wid = t >> 6;    // wid 0..7
  int c5 = lane & 31, h = lane >> 5;
  __shared__ unsigned short Ks[2][64 * 64];
  __shared__ unsigned short Vs[2][64 * 64];

  // Q frags (B-operand): col=q=c5 (row idx), k-elements d = dK*16 + h*8 + e
  const unsigned short* Qp = Qw + ((long)bh * 2048 + qt * 256 + wid * 32 + c5) * 64 + h * 8;
  bf16x8 qf[4];
#pragma unroll
  for (int dK = 0; dK < 4; dK++) qf[dK] = *(const bf16x8*)(Qp + dK * 16);

  f32x16 oacc0 = {}, oacc1 = {};
  float ls0 = 0.f, ls1 = 0.f, ls2 = 0.f, ls3 = 0.f;

  const unsigned short* Kbase = Kw + (long)bh * 2048 * 64;
  const unsigned short* Vbase = Vtw + (long)bh * 64 * 2048;

  // K tile: [64 kv][64 d], V tile: [64 d][64 kv]; 16B-chunk XOR swizzle (chunk ^= row&7)
  // via pre-swizzled GLOBAL source + linear LDS dest. 512 threads: 1 K + 1 V chunk each.
#define STAGE(jt_, buf_)                                                              \
  {                                                                                   \
    int row = t >> 3, ch = t & 7;                                                     \
    int sw = ch ^ (row & 7);                                                          \
    gl_lds16(Kbase + (long)((jt_) * 64 + row) * 64 + sw * 8, &Ks[buf_][t * 8]);       \
    gl_lds16(Vbase + (long)row * 2048 + (jt_) * 64 + sw * 8, &Vs[buf_][t * 8]);       \
  }

  STAGE(0, 0);

  union FR { int i[4]; bf16x8 v; };

  for (int jt = 0; jt < 32; jt++) {
    int buf = jt & 1;
    __syncthreads();  // drains own vmcnt -> buf ready; prev reads of buf^1 complete
    if (jt + 1 < 32) STAGE(jt + 1, buf ^ 1);

    // S^T = K . Q^T : A-frag = K rows (kv), B-frag = Q rows (q)
    f32x16 s0 = {}, s1 = {};
#pragma unroll
    for (int dK = 0; dK < 4; dK++) {
      int sw = ((dK * 2 + h) ^ (c5 & 7)) * 8;
      bf16x8 k0 = *(const bf16x8*)(&Ks[buf][c5 * 64 + sw]);
      bf16x8 k1 = *(const bf16x8*)(&Ks[buf][c5 * 64 + sw + 2048]);  // kv row +32
      s0 = MFMA32(k0, qf[dK], s0);
      s1 = MFMA32(k1, qf[dK], s1);
    }

    // p = 2^S, lane-local row-sum partials, HW-pack pairs to bf16 dwords
    int pk[2][4][2];
#pragma unroll
    for (int q2 = 0; q2 < 4; q2++) {
      float a0 = exp2_fast(s0[q2 * 4 + 0]), a1 = exp2_fast(s0[q2 * 4 + 1]);
      float a2 = exp2_fast(s0[q2 * 4 + 2]), a3 = exp2_fast(s0[q2 * 4 + 3]);
      ls0 += a0 + a1; ls1 += a2 + a3;
      pk[0][q2][0] = cvt_pk_bf16(a0, a1);
      pk[0][q2][1] = cvt_pk_bf16(a2, a3);
      float b0 = exp2_fast(s1[q2 * 4 + 0]), b1 = exp2_fast(s1[q2 * 4 + 1]);
      float b2 = exp2_fast(s1[q2 * 4 + 2]), b3 = exp2_fast(s1[q2 * 4 + 3]);
      ls2 += b0 + b1; ls3 += b2 + b3;
      pk[1][q2][0] = cvt_pk_bf16(b0, b1);
      pk[1][q2][1] = cvt_pk_bf16(b2, b3);
    }

    // Redistribute P across the h-bit with permlane32_swap and run PV: O^T += V^T . P.
#pragma unroll
    for (int kblk = 0; kblk < 4; kblk++) {
      int kvb = kblk >> 1, e2c = (kblk & 1) * 2;
      u32x2 p0 = __builtin_amdgcn_permlane32_swap((unsigned)pk[kvb][e2c][0],
                                                  (unsigned)pk[kvb][e2c + 1][0], false, false);
      u32x2 p1 = __builtin_amdgcn_permlane32_swap((unsigned)pk[kvb][e2c][1],
                                                  (unsigned)pk[kvb][e2c + 1][1], false, false);
      FR fr;
      fr.i[0] = (int)p0[0];  // w0
      fr.i[1] = (int)p1[0];  // w1
      fr.i[2] = (int)p0[1];  // w2
      fr.i[3] = (int)p1[1];  // w3
      int sw = ((kblk * 2 + h) ^ (c5 & 7)) * 8;
      bf16x8 v0 = *(const bf16x8*)(&Vs[buf][c5 * 64 + sw]);
      bf16x8 v1 = *(const bf16x8*)(&Vs[buf][c5 * 64 + sw + 2048]);  // d row +32
      oacc0 = MFMA32(v0, fr.v, oacc0);
      oacc1 = MFMA32(v1, fr.v, oacc1);
    }
  }
#undef STAGE

  // epilogue: full row-sum (other 32 kv in h-partner lane), normalize, store
  float lsum = ls0 + ls1 + ls2 + ls3;
  lsum += __shfl_xor(lsum, 32);
  float inv = 1.0f / lsum;
  int b = bh >> 4, hh = bh & 15;
  long row = (long)b * 2048 + qt * 256 + wid * 32 + c5;
  unsigned short* orow = Ow + row * 1024 + hh * 64;
#pragma unroll
  for (int dblk = 0; dblk < 2; dblk++) {
#pragma unroll
    for (int q2 = 0; q2 < 4; q2++) {
      float o0 = (dblk ? oacc1 : oacc0)[q2 * 4 + 0] * inv;
      float o1 = (dblk ? oacc1 : oacc0)[q2 * 4 + 1] * inv;
      float o2 = (dblk ? oacc1 : oacc0)[q2 * 4 + 2] * inv;
      float o3 = (dblk ? oacc1 : oacc0)[q2 * 4 + 3] * inv;
      ushort4 pkv;
      pkv.x = f2b(o0); pkv.y = f2b(o1); pkv.z = f2b(o2); pkv.w = f2b(o3);
      *(ushort4*)(orow + dblk * 32 + q2 * 8 + h * 4) = pkv;
    }
  }
}

// ==================== output projection + bias ====================
__global__ __launch_bounds__(256) void gemm_out(const unsigned short* __restrict__ Ao,
                                                const unsigned short* __restrict__ wto,
                                                const float* __restrict__ bias,
                                                float* __restrict__ out) {
  __shared__ unsigned short As[3 * 128 * 32], Bs[3 * 128 * 32];
  int m0 = blockIdx.x * 128;
  int n0 = blockIdx.y * 128;
  int lane = threadIdx.x & 63, wid = threadIdx.x >> 6;
  f32x4 acc[4][4] = {};
  gemm_tile_128(Ao, wto, m0, n0, acc, As, Bs, lane, wid);
  const int wr = wid >> 1, wc = wid & 1;
  const int c = lane & 15, g = lane >> 4;
#pragma unroll
  for (int mi = 0; mi < 4; mi++)
#pragma unroll
    for (int ni = 0; ni < 4; ni++) {
      int col = n0 + wc * 64 + ni * 16 + c;
      float bv = bias[col];
#pragma unroll
      for (int r = 0; r < 4; r++) {
        int row = m0 + wr * 64 + mi * 16 + g * 4 + r;
        out[(long)row * 1024 + col] = acc[mi][ni][r] + bv;
      }
    }
}

// ==================== launch ====================
extern "C" void kernel_launch(void* const* d_in, const int* in_sizes, int n_in,
                              void* d_out, int out_size, void* d_ws, size_t ws_size,
                              hipStream_t stream) {
  const float* x  = (const float*)d_in[0];
  const float* Wq = (const float*)d_in[1];
  const float* Wk = (const float*)d_in[2];
  const float* Wv = (const float*)d_in[3];
  const float* Wo = (const float*)d_in[4];
  const float* bo = (const float*)d_in[5];
  float* out = (float*)d_out;

  char* ws = (char*)d_ws;
  unsigned short* xb  = (unsigned short*)(ws);                              // 16 MB: x bf16 [8192][1024]
  unsigned short* wtq = (unsigned short*)(ws + 16777216);                   // 2 MB each, transposed [N][K]
  unsigned short* wtk = (unsigned short*)(ws + 16777216 + 2097152);
  unsigned short* wtv = (unsigned short*)(ws + 16777216 + 2 * 2097152);
  unsigned short* wto = (unsigned short*)(ws + 16777216 + 3 * 2097152);
  unsigned short* Qw  = (unsigned short*)(ws + 25165824);                   // [bh][i][d]
  unsigned short* Kw  = (unsigned short*)(ws + 25165824 + 16777216);        // [bh][j][d]
  unsigned short* Vtw = (unsigned short*)(ws + 25165824 + 2 * 16777216);    // [bh][d][j]
  unsigned short* Aow = xb;  // alias: xb fully consumed by gemm_qkv before attn writes

  convert_x<<<8192, 256, 0, stream>>>(x, xb);
  transpose_w<<<dim3(16, 16, 4), 256, 0, stream>>>(Wq, Wk, Wv, Wo, wtq, wtk, wtv, wto);
  gemm_qkv<<<dim3(64, 24), 256, 0, stream>>>(xb, wtq, wtk, wtv, Qw, Kw, Vtw);
  attn<<<dim3(8, 64), 512, 0, stream>>>(Qw, Kw, Vtw, Aow);
  gemm_out<<<dim3(64, 8), 256, 0, stream>>>(Aow, wto, bo, out);
}